// Round 4
// baseline (113.494 us; speedup 1.0000x reference)
//
#include <hip/hip_runtime.h>
#include <hip/hip_bf16.h>
#include <string.h>

constexpr int B_ = 8;
constexpr int N_ = 2048;
constexpr int FIN = 128;
constexpr int FOUT = 64;
constexpr float ALPHA_ = 0.2f;
constexpr float NEG_INF_ = -9000000000000000.0f;

typedef __attribute__((ext_vector_type(8))) short bf16x8;
typedef __attribute__((ext_vector_type(4))) float f32x4;

static __device__ __forceinline__ unsigned short f2bf(float x) {
  unsigned int u = __float_as_uint(x);
  unsigned int r = u + 0x7fffu + ((u >> 16) & 1u);
  return (unsigned short)(r >> 16);
}

// ---------------- Kernel 1: Wh^T (bf16) + si/sj (f32, exact) ----------------
__global__ __launch_bounds__(256) void k_wh(
    const float* __restrict__ h, const float* __restrict__ W,
    const float* __restrict__ a, unsigned short* __restrict__ WhT,
    float* __restrict__ si, float* __restrict__ sj) {
  const int lane = threadIdx.x & 63;
  const int wv = threadIdx.x >> 6;
  const int grow0 = blockIdx.x * 32 + wv * 8;  // b*N + n, 8 rows
  const int f = lane;
  float acc[8] = {0.f, 0.f, 0.f, 0.f, 0.f, 0.f, 0.f, 0.f};
  const float* hp = h + (size_t)grow0 * FIN;
#pragma unroll 4
  for (int k = 0; k < FIN; k += 4) {
    float w0 = W[k * FOUT + f];
    float w1 = W[(k + 1) * FOUT + f];
    float w2 = W[(k + 2) * FOUT + f];
    float w3 = W[(k + 3) * FOUT + f];
#pragma unroll
    for (int r = 0; r < 8; ++r) {
      float4 hv = *(const float4*)(hp + r * FIN + k);
      acc[r] = fmaf(hv.x, w0, acc[r]);
      acc[r] = fmaf(hv.y, w1, acc[r]);
      acc[r] = fmaf(hv.z, w2, acc[r]);
      acc[r] = fmaf(hv.w, w3, acc[r]);
    }
  }
  const float a1 = a[f], a2 = a[FOUT + f];
#pragma unroll
  for (int r = 0; r < 8; ++r) {
    float p1 = acc[r] * a1;
    float p2 = acc[r] * a2;
#pragma unroll
    for (int off = 32; off; off >>= 1) {
      p1 += __shfl_xor(p1, off);
      p2 += __shfl_xor(p2, off);
    }
    if (lane == 0) {
      si[grow0 + r] = p1;
      sj[grow0 + r] = p2;
    }
  }
  const int b = grow0 >> 11;
  const int n0 = grow0 & (N_ - 1);
  __align__(16) unsigned short u[8];
#pragma unroll
  for (int r = 0; r < 8; ++r) u[r] = f2bf(acc[r]);
  *(bf16x8*)&WhT[(((size_t)(b * FOUT + f)) << 11) + n0] = *(const bf16x8*)u;
}

// ---------------- Kernel 2: adj -> bitmasks ----------------
__global__ __launch_bounds__(256) void k_pack(
    const int* __restrict__ adj, unsigned long long* __restrict__ mask_rm,
    unsigned int* __restrict__ mask_t) {
  const int lane = threadIdx.x & 63;
  const int wv = threadIdx.x >> 6;
  const int r = blockIdx.x * 4 + wv;
  const int* row = adj + (size_t)r * N_;
  unsigned int wacc = 0;
#pragma unroll
  for (int it = 0; it < 32; ++it) {
    int v = row[it * 64 + lane];
    unsigned long long bm = __ballot(v > 0);
    if (lane == 0) mask_rm[r * 32 + it] = bm;
    wacc |= ((unsigned int)(v > 0)) << it;
  }
  mask_t[r * 64 + lane] = wacc;
}

// ---------------- Kernel 3: per-row softmax stats ----------------
__global__ __launch_bounds__(256) void k_stats(
    const unsigned int* __restrict__ mask_t, const float* __restrict__ si,
    const float* __restrict__ sj, float* __restrict__ mrow,
    float* __restrict__ rrow) {
  const int lane = threadIdx.x & 63;
  const int wv = threadIdx.x >> 6;
  const int row = blockIdx.x * 4 + wv;  // b*N + i
  const int b = row >> 11;
  const int i = row & (N_ - 1);
  const unsigned int w32 = mask_t[i * 64 + lane];
  const float* sjb = sj + ((size_t)b << 11);
  float sjv[32];
  float M = -3.0e38f;
#pragma unroll
  for (int it = 0; it < 32; ++it) {
    sjv[it] = sjb[it * 64 + lane];
    if ((w32 >> it) & 1u) M = fmaxf(M, sjv[it]);
  }
#pragma unroll
  for (int off = 32; off; off >>= 1) M = fmaxf(M, __shfl_xor(M, off));
  const float siv = si[row];
  const float e0 = siv + M;
  const float m = e0 > 0.f ? e0 : ALPHA_ * e0;
  float s = 0.f;
#pragma unroll
  for (int it = 0; it < 32; ++it) {
    float e = siv + sjv[it];
    float v = e > 0.f ? e : ALPHA_ * e;
    float p = __expf(v - m);
    s += ((w32 >> it) & 1u) ? p : 0.f;
  }
#pragma unroll
  for (int off = 32; off; off >>= 1) s += __shfl_xor(s, off);
  if (lane == 0) {
    mrow[row] = m;
    rrow[row] = 1.f / s;
  }
}

// ------- Kernel 4: barrier-free, LDS-free att write + h' via MFMA -------
// Block = 64 att rows of one batch, 8 waves. Wave (rt = wv&3, dup = wv>>2):
// owns 16-row strip rt; computes its MFMA A-strip (16 x 128 att values) in
// registers (2x duplicated across the dup pair); dup selects which two
// 16-col B tiles it multiplies and which half of the att j-range it stores.
// B fragments load directly from L2-resident WhT in MFMA layout. No LDS,
// no __syncthreads: waves stream independently; HBM write BW is the wall.
__global__ __launch_bounds__(512) void k_main(
    const unsigned short* __restrict__ WhT,
    const unsigned long long* __restrict__ mask_rm,
    const float* __restrict__ si, const float* __restrict__ sjg,
    const float* __restrict__ mrow, const float* __restrict__ rrow,
    float* __restrict__ att_out, float* __restrict__ h_out) {
  const int bid = blockIdx.x;          // 256 blocks
  const int b = bid & 7;               // batch == XCD (round-robin dispatch)
  const int i0 = (bid >> 3) * 64;

  const int tid = threadIdx.x;
  const int lane = tid & 63;
  const int wv = tid >> 6;
  const int rt = wv & 3;   // 16-row strip
  const int dup = wv >> 2; // 0: cols 0-31 & stores ks 0,1 ; 1: cols 32-63 & ks 2,3
  const int rl = lane & 15;
  const int hi = lane >> 4;

  const int row = i0 + rt * 16 + rl;   // att row (i) for this lane's A frags
  const int grow = (b << 11) + row;    // b*N + i
  const float sir = si[grow];
  const float mK = mrow[grow] * 1.44269504f;
  const float rr = rrow[grow];
  const float* __restrict__ sjb = sjg + ((size_t)b << 11);
  const unsigned char* __restrict__ maskb =
      (const unsigned char*)mask_rm + row * 256;  // 2048 bits per row

  const int f0 = dup * 32 + rl;        // B cols for this wave's two tiles
  const int f1 = f0 + 16;
  const unsigned short* __restrict__ wb0 = WhT + (((size_t)(b * FOUT + f0)) << 11);
  const unsigned short* __restrict__ wb1 = WhT + (((size_t)(b * FOUT + f1)) << 11);

  f32x4 acc0 = {0.f, 0.f, 0.f, 0.f};
  f32x4 acc1 = {0.f, 0.f, 0.f, 0.f};

  for (int t = 0; t < N_ / 128; ++t) {
    const int j0 = t * 128;
    const uint4 mr = *(const uint4*)(maskb + (j0 >> 3));  // 128 mask bits
    const unsigned int mw[4] = {mr.x, mr.y, mr.z, mr.w};
    bf16x8 afr[4];

#pragma unroll
    for (int ks = 0; ks < 4; ++ks) {
      const int jb = j0 + ks * 32 + hi * 8;  // this lane's 8 j's for step ks
      const float4 s0 = *(const float4*)(sjb + jb);
      const float4 s1 = *(const float4*)(sjb + jb + 4);
      const unsigned int mby = (mw[ks] >> (hi * 8)) & 0xffu;
      const float sjl[8] = {s0.x, s0.y, s0.z, s0.w, s1.x, s1.y, s1.z, s1.w};
      float av[8];
#pragma unroll
      for (int e = 0; e < 8; ++e) {
        float ev = sir + sjl[e];
        float v = fmaxf(ev, ALPHA_ * ev);               // LeakyReLU
        float p = exp2f(fmaf(v, 1.44269504f, -mK)) * rr;
        av[e] = ((mby >> e) & 1u) ? p : 0.f;
      }
      if ((ks >> 1) == dup) {  // each att value stored exactly once
        float* ao = att_out + (((size_t)grow) << 11) + jb;
        *(float4*)ao = make_float4(av[0], av[1], av[2], av[3]);
        *(float4*)(ao + 4) = make_float4(av[4], av[5], av[6], av[7]);
      }
      __align__(16) unsigned short u[8];
#pragma unroll
      for (int e = 0; e < 8; ++e) u[e] = f2bf(av[e]);
      afr[ks] = *(const bf16x8*)u;
    }

#pragma unroll
    for (int ks = 0; ks < 4; ++ks) {
      const int jb = j0 + ks * 32 + hi * 8;
      bf16x8 bv0 = *(const bf16x8*)(wb0 + jb);
      bf16x8 bv1 = *(const bf16x8*)(wb1 + jb);
      acc0 = __builtin_amdgcn_mfma_f32_16x16x32_bf16(afr[ks], bv0, acc0, 0, 0, 0);
      acc1 = __builtin_amdgcn_mfma_f32_16x16x32_bf16(afr[ks], bv1, acc1, 0, 0, 0);
    }
  }

  // epilogue: elu + store. C/D: col = lane&15, row = (lane>>4)*4 + reg.
  const int rowb = i0 + rt * 16 + hi * 4;
  const int colb0 = dup * 32 + rl;
  const int colb1 = colb0 + 16;
#pragma unroll
  for (int qq = 0; qq < 4; ++qq) {
    float x0 = acc0[qq];
    float x1 = acc1[qq];
    float o0 = x0 > 0.f ? x0 : __expf(x0) - 1.f;
    float o1 = x1 > 0.f ? x1 : __expf(x1) - 1.f;
    const size_t base = ((size_t)((b << 11) + rowb + qq)) << 6;
    h_out[base + colb0] = o0;
    h_out[base + colb1] = o1;
  }
}

extern "C" void kernel_launch(void* const* d_in, const int* in_sizes, int n_in,
                              void* d_out, int out_size, void* d_ws, size_t ws_size,
                              hipStream_t stream) {
  const float* h = (const float*)d_in[0];
  const int* adj = (const int*)d_in[1];
  const float* W = (const float*)d_in[2];
  const float* a = (const float*)d_in[3];

  float* out = (float*)d_out;
  float* h_out = out;                             // B*N*FOUT
  float* att_out = out + (size_t)B_ * N_ * FOUT;  // B*N*N

  unsigned short* WhT = (unsigned short*)d_ws;                       // 2 MB
  float* si = (float*)((char*)d_ws + (size_t)2 * 1024 * 1024);       // 64 KB
  float* sj = si + B_ * N_;                                          // 64 KB
  float* mrow = sj + B_ * N_;                                        // 64 KB
  float* rrow = mrow + B_ * N_;                                      // 64 KB
  unsigned long long* mask_rm = (unsigned long long*)(rrow + B_ * N_);  // 512 KB
  unsigned int* mask_t = (unsigned int*)((char*)mask_rm + (size_t)N_ * 32 * 8);  // 512 KB

  k_wh<<<B_ * N_ / 32, 256, 0, stream>>>(h, W, a, WhT, si, sj);
  k_pack<<<N_ / 4, 256, 0, stream>>>(adj, mask_rm, mask_t);
  k_stats<<<B_ * N_ / 4, 256, 0, stream>>>(mask_t, si, sj, mrow, rrow);
  k_main<<<256, 512, 0, stream>>>(WhT, mask_rm, si, sj, mrow, rrow,
                                  att_out, h_out);
}

// Round 6
// 105.112 us; speedup vs baseline: 1.0797x; 1.0797x over previous
//
#include <hip/hip_runtime.h>
#include <hip/hip_bf16.h>
#include <string.h>

constexpr int B_ = 8;
constexpr int N_ = 2048;
constexpr int FIN = 128;
constexpr int FOUT = 64;
constexpr float ALPHA_ = 0.2f;
constexpr float NEG_INF_ = -9000000000000000.0f;

typedef __attribute__((ext_vector_type(8))) short bf16x8;
typedef __attribute__((ext_vector_type(4))) float f32x4;

static __device__ __forceinline__ unsigned short f2bf(float x) {
  unsigned int u = __float_as_uint(x);
  unsigned int r = u + 0x7fffu + ((u >> 16) & 1u);
  return (unsigned short)(r >> 16);
}

// ---------------- Kernel 1: Wh^T (bf16) + si/sj (f32, exact) ----------------
__global__ __launch_bounds__(256) void k_wh(
    const float* __restrict__ h, const float* __restrict__ W,
    const float* __restrict__ a, unsigned short* __restrict__ WhT,
    float* __restrict__ si, float* __restrict__ sj) {
  const int lane = threadIdx.x & 63;
  const int wv = threadIdx.x >> 6;
  const int grow0 = blockIdx.x * 32 + wv * 8;  // b*N + n, 8 rows
  const int f = lane;
  float acc[8] = {0.f, 0.f, 0.f, 0.f, 0.f, 0.f, 0.f, 0.f};
  const float* hp = h + (size_t)grow0 * FIN;
#pragma unroll 4
  for (int k = 0; k < FIN; k += 4) {
    float w0 = W[k * FOUT + f];
    float w1 = W[(k + 1) * FOUT + f];
    float w2 = W[(k + 2) * FOUT + f];
    float w3 = W[(k + 3) * FOUT + f];
#pragma unroll
    for (int r = 0; r < 8; ++r) {
      float4 hv = *(const float4*)(hp + r * FIN + k);
      acc[r] = fmaf(hv.x, w0, acc[r]);
      acc[r] = fmaf(hv.y, w1, acc[r]);
      acc[r] = fmaf(hv.z, w2, acc[r]);
      acc[r] = fmaf(hv.w, w3, acc[r]);
    }
  }
  const float a1 = a[f], a2 = a[FOUT + f];
#pragma unroll
  for (int r = 0; r < 8; ++r) {
    float p1 = acc[r] * a1;
    float p2 = acc[r] * a2;
#pragma unroll
    for (int off = 32; off; off >>= 1) {
      p1 += __shfl_xor(p1, off);
      p2 += __shfl_xor(p2, off);
    }
    if (lane == 0) {
      si[grow0 + r] = p1;
      sj[grow0 + r] = p2;
    }
  }
  const int b = grow0 >> 11;
  const int n0 = grow0 & (N_ - 1);
  __align__(16) unsigned short u[8];
#pragma unroll
  for (int r = 0; r < 8; ++r) u[r] = f2bf(acc[r]);
  *(bf16x8*)&WhT[(((size_t)(b * FOUT + f)) << 11) + n0] = *(const bf16x8*)u;
}

// ---------------- Kernel 2: adj -> bitmasks ----------------
__global__ __launch_bounds__(256) void k_pack(
    const int* __restrict__ adj, unsigned long long* __restrict__ mask_rm,
    unsigned int* __restrict__ mask_t) {
  const int lane = threadIdx.x & 63;
  const int wv = threadIdx.x >> 6;
  const int r = blockIdx.x * 4 + wv;
  const int* row = adj + (size_t)r * N_;
  unsigned int wacc = 0;
#pragma unroll
  for (int it = 0; it < 32; ++it) {
    int v = row[it * 64 + lane];
    unsigned long long bm = __ballot(v > 0);
    if (lane == 0) mask_rm[r * 32 + it] = bm;
    wacc |= ((unsigned int)(v > 0)) << it;
  }
  mask_t[r * 64 + lane] = wacc;
}

// ---------------- Kernel 3: per-row softmax stats ----------------
__global__ __launch_bounds__(256) void k_stats(
    const unsigned int* __restrict__ mask_t, const float* __restrict__ si,
    const float* __restrict__ sj, float* __restrict__ mrow,
    float* __restrict__ rrow) {
  const int lane = threadIdx.x & 63;
  const int wv = threadIdx.x >> 6;
  const int row = blockIdx.x * 4 + wv;  // b*N + i
  const int b = row >> 11;
  const int i = row & (N_ - 1);
  const unsigned int w32 = mask_t[i * 64 + lane];
  const float* sjb = sj + ((size_t)b << 11);
  float sjv[32];
  float M = -3.0e38f;
#pragma unroll
  for (int it = 0; it < 32; ++it) {
    sjv[it] = sjb[it * 64 + lane];
    if ((w32 >> it) & 1u) M = fmaxf(M, sjv[it]);
  }
#pragma unroll
  for (int off = 32; off; off >>= 1) M = fmaxf(M, __shfl_xor(M, off));
  const float siv = si[row];
  const float e0 = siv + M;
  const float m = e0 > 0.f ? e0 : ALPHA_ * e0;
  float s = 0.f;
#pragma unroll
  for (int it = 0; it < 32; ++it) {
    float e = siv + sjv[it];
    float v = e > 0.f ? e : ALPHA_ * e;
    float p = __expf(v - m);
    s += ((w32 >> it) & 1u) ? p : 0.f;
  }
#pragma unroll
  for (int off = 32; off; off >>= 1) s += __shfl_xor(s, off);
  if (lane == 0) {
    mrow[row] = m;
    rrow[row] = 1.f / s;
  }
}

// ------- Kernel 4: wave-j-sliced, barrier-free-loop att + h' via MFMA -------
// Block = 32 att rows of one batch, 8 waves. Wave wv owns j in
// [wv*256, wv*256+256) for ALL 32 rows: computes att there (once), nt-stores
// it, and accumulates partial C (32x64) over its slice in registers.
// End: one LDS tree-reduction over the 8 partials, then elu + store.
constexpr int TI = 32;

__global__ __launch_bounds__(512, 4) void k_main(
    const unsigned short* __restrict__ WhT,
    const unsigned long long* __restrict__ mask_rm,
    const float* __restrict__ si, const float* __restrict__ sjg,
    const float* __restrict__ mrow, const float* __restrict__ rrow,
    float* __restrict__ att_out, float* __restrict__ h_out) {
  __shared__ float red[4][TI][FOUT];  // 32 KB

  const int bid = blockIdx.x;  // 512 blocks
  const int swz = (bid & 7) * 64 + (bid >> 3);  // XCD <-> batch
  const int b = swz >> 6;
  const int i0 = (swz & 63) * TI;

  const int tid = threadIdx.x;
  const int lane = tid & 63;
  const int wv = tid >> 6;
  const int rl = lane & 15;
  const int hi = lane >> 4;
  const int jsl = wv * 256;  // this wave's j-slice

  // per-lane row constants for the two 16-row strips
  const int grow0 = (b << 11) + i0 + rl;
  const int grow1 = grow0 + 16;
  const float sir0 = si[grow0], sir1 = si[grow1];
  const float mK0 = mrow[grow0] * 1.44269504f, mK1 = mrow[grow1] * 1.44269504f;
  const float rr0 = rrow[grow0], rr1 = rrow[grow1];
  const float* __restrict__ sjb = sjg + ((size_t)b << 11);

  // mask bytes for this lane's two rows, this wave's 256-j slice (32 B each)
  const unsigned char* maskb = (const unsigned char*)mask_rm;
  const uint4 mA0 = *(const uint4*)(maskb + (i0 + rl) * 256 + (jsl >> 3));
  const uint4 mA1 = *(const uint4*)(maskb + (i0 + rl) * 256 + (jsl >> 3) + 16);
  const uint4 mB0 = *(const uint4*)(maskb + (i0 + 16 + rl) * 256 + (jsl >> 3));
  const uint4 mB1 = *(const uint4*)(maskb + (i0 + 16 + rl) * 256 + (jsl >> 3) + 16);
  const unsigned int mw0[8] = {mA0.x, mA0.y, mA0.z, mA0.w, mA1.x, mA1.y, mA1.z, mA1.w};
  const unsigned int mw1[8] = {mB0.x, mB0.y, mB0.z, mB0.w, mB1.x, mB1.y, mB1.z, mB1.w};

  // B-fragment base pointers: col tile ct -> WhT row ct*16+rl, this j-slice
  const unsigned short* wbp[4];
#pragma unroll
  for (int ct = 0; ct < 4; ++ct)
    wbp[ct] = WhT + (((size_t)(b * FOUT + ct * 16 + rl)) << 11) + jsl + hi * 8;

  float* ao0 = att_out + (((size_t)grow0) << 11) + jsl + hi * 8;
  float* ao1 = att_out + (((size_t)grow1) << 11) + jsl + hi * 8;

  f32x4 acc[2][4];
#pragma unroll
  for (int rt = 0; rt < 2; ++rt)
#pragma unroll
    for (int ct = 0; ct < 4; ++ct) acc[rt][ct] = (f32x4){0.f, 0.f, 0.f, 0.f};

#pragma unroll
  for (int ks = 0; ks < 8; ++ks) {
    const int jb = jsl + ks * 32 + hi * 8;  // this lane's 8 j's
    const float4 s0 = *(const float4*)(sjb + jb);
    const float4 s1 = *(const float4*)(sjb + jb + 4);
    const float sjl[8] = {s0.x, s0.y, s0.z, s0.w, s1.x, s1.y, s1.z, s1.w};

    bf16x8 afr0, afr1;
    {
      const unsigned int mby = (mw0[ks] >> (hi * 8)) & 0xffu;
      float av[8];
#pragma unroll
      for (int e = 0; e < 8; ++e) {
        float ev = sir0 + sjl[e];
        float v = fmaxf(ev, ALPHA_ * ev);
        float p = exp2f(fmaf(v, 1.44269504f, -mK0)) * rr0;
        av[e] = ((mby >> e) & 1u) ? p : 0.f;
      }
      f32x4 v0 = {av[0], av[1], av[2], av[3]};
      f32x4 v1 = {av[4], av[5], av[6], av[7]};
      __builtin_nontemporal_store(v0, (f32x4*)(ao0 + ks * 32));
      __builtin_nontemporal_store(v1, (f32x4*)(ao0 + ks * 32 + 4));
      __align__(16) unsigned short u[8];
#pragma unroll
      for (int e = 0; e < 8; ++e) u[e] = f2bf(av[e]);
      afr0 = *(const bf16x8*)u;
    }
    {
      const unsigned int mby = (mw1[ks] >> (hi * 8)) & 0xffu;
      float av[8];
#pragma unroll
      for (int e = 0; e < 8; ++e) {
        float ev = sir1 + sjl[e];
        float v = fmaxf(ev, ALPHA_ * ev);
        float p = exp2f(fmaf(v, 1.44269504f, -mK1)) * rr1;
        av[e] = ((mby >> e) & 1u) ? p : 0.f;
      }
      f32x4 v0 = {av[0], av[1], av[2], av[3]};
      f32x4 v1 = {av[4], av[5], av[6], av[7]};
      __builtin_nontemporal_store(v0, (f32x4*)(ao1 + ks * 32));
      __builtin_nontemporal_store(v1, (f32x4*)(ao1 + ks * 32 + 4));
      __align__(16) unsigned short u[8];
#pragma unroll
      for (int e = 0; e < 8; ++e) u[e] = f2bf(av[e]);
      afr1 = *(const bf16x8*)u;
    }

#pragma unroll
    for (int ct = 0; ct < 4; ++ct) {
      bf16x8 bv = *(const bf16x8*)(wbp[ct] + ks * 32);
      acc[0][ct] = __builtin_amdgcn_mfma_f32_16x16x32_bf16(afr0, bv, acc[0][ct], 0, 0, 0);
      acc[1][ct] = __builtin_amdgcn_mfma_f32_16x16x32_bf16(afr1, bv, acc[1][ct], 0, 0, 0);
    }
  }

  // ---- cross-wave partial-C reduction via LDS (tiles: row=rt*16+hi*4+reg, col=ct*16+rl) ----
  if (wv < 4) {
#pragma unroll
    for (int rt = 0; rt < 2; ++rt)
#pragma unroll
      for (int ct = 0; ct < 4; ++ct)
#pragma unroll
        for (int rg = 0; rg < 4; ++rg)
          red[wv][rt * 16 + hi * 4 + rg][ct * 16 + rl] = acc[rt][ct][rg];
  }
  __syncthreads();
  if (wv >= 4) {
#pragma unroll
    for (int rt = 0; rt < 2; ++rt)
#pragma unroll
      for (int ct = 0; ct < 4; ++ct)
#pragma unroll
        for (int rg = 0; rg < 4; ++rg)
          red[wv - 4][rt * 16 + hi * 4 + rg][ct * 16 + rl] += acc[rt][ct][rg];
  }
  __syncthreads();

#pragma unroll
  for (int k = tid; k < TI * FOUT; k += 512) {
    const int r = k >> 6;
    const int c = k & 63;
    float x = red[0][r][c] + red[1][r][c] + red[2][r][c] + red[3][r][c];
    float o = x > 0.f ? x : __expf(x) - 1.f;
    h_out[(((size_t)((b << 11) + i0 + r)) << 6) + c] = o;
  }
}

extern "C" void kernel_launch(void* const* d_in, const int* in_sizes, int n_in,
                              void* d_out, int out_size, void* d_ws, size_t ws_size,
                              hipStream_t stream) {
  const float* h = (const float*)d_in[0];
  const int* adj = (const int*)d_in[1];
  const float* W = (const float*)d_in[2];
  const float* a = (const float*)d_in[3];

  float* out = (float*)d_out;
  float* h_out = out;                             // B*N*FOUT
  float* att_out = out + (size_t)B_ * N_ * FOUT;  // B*N*N

  unsigned short* WhT = (unsigned short*)d_ws;                       // 2 MB
  float* si = (float*)((char*)d_ws + (size_t)2 * 1024 * 1024);       // 64 KB
  float* sj = si + B_ * N_;                                          // 64 KB
  float* mrow = sj + B_ * N_;                                        // 64 KB
  float* rrow = mrow + B_ * N_;                                      // 64 KB
  unsigned long long* mask_rm = (unsigned long long*)(rrow + B_ * N_);  // 512 KB
  unsigned int* mask_t = (unsigned int*)((char*)mask_rm + (size_t)N_ * 32 * 8);  // 512 KB

  k_wh<<<B_ * N_ / 32, 256, 0, stream>>>(h, W, a, WhT, si, sj);
  k_pack<<<N_ / 4, 256, 0, stream>>>(adj, mask_rm, mask_t);
  k_stats<<<B_ * N_ / 4, 256, 0, stream>>>(mask_t, si, sj, mrow, rrow);
  k_main<<<B_ * (N_ / TI), 512, 0, stream>>>(WhT, mask_rm, si, sj, mrow, rrow,
                                             att_out, h_out);
}

// Round 7
// 97.956 us; speedup vs baseline: 1.1586x; 1.0731x over previous
//
#include <hip/hip_runtime.h>
#include <hip/hip_bf16.h>
#include <string.h>

constexpr int B_ = 8;
constexpr int N_ = 2048;
constexpr int FIN = 128;
constexpr int FOUT = 64;
constexpr float ALPHA_ = 0.2f;
constexpr float NEG_INF_ = -9000000000000000.0f;

typedef __attribute__((ext_vector_type(8))) short bf16x8;
typedef __attribute__((ext_vector_type(4))) float f32x4;

static __device__ __forceinline__ unsigned short f2bf(float x) {
  unsigned int u = __float_as_uint(x);
  unsigned int r = u + 0x7fffu + ((u >> 16) & 1u);
  return (unsigned short)(r >> 16);
}

// ---------------- Kernel 1: Wh^T (bf16) + si/sj (f32, exact) ----------------
__global__ __launch_bounds__(256) void k_wh(
    const float* __restrict__ h, const float* __restrict__ W,
    const float* __restrict__ a, unsigned short* __restrict__ WhT,
    float* __restrict__ si, float* __restrict__ sj) {
  const int lane = threadIdx.x & 63;
  const int wv = threadIdx.x >> 6;
  const int grow0 = blockIdx.x * 32 + wv * 8;  // b*N + n, 8 rows
  const int f = lane;
  float acc[8] = {0.f, 0.f, 0.f, 0.f, 0.f, 0.f, 0.f, 0.f};
  const float* hp = h + (size_t)grow0 * FIN;
#pragma unroll 4
  for (int k = 0; k < FIN; k += 4) {
    float w0 = W[k * FOUT + f];
    float w1 = W[(k + 1) * FOUT + f];
    float w2 = W[(k + 2) * FOUT + f];
    float w3 = W[(k + 3) * FOUT + f];
#pragma unroll
    for (int r = 0; r < 8; ++r) {
      float4 hv = *(const float4*)(hp + r * FIN + k);
      acc[r] = fmaf(hv.x, w0, acc[r]);
      acc[r] = fmaf(hv.y, w1, acc[r]);
      acc[r] = fmaf(hv.z, w2, acc[r]);
      acc[r] = fmaf(hv.w, w3, acc[r]);
    }
  }
  const float a1 = a[f], a2 = a[FOUT + f];
#pragma unroll
  for (int r = 0; r < 8; ++r) {
    float p1 = acc[r] * a1;
    float p2 = acc[r] * a2;
#pragma unroll
    for (int off = 32; off; off >>= 1) {
      p1 += __shfl_xor(p1, off);
      p2 += __shfl_xor(p2, off);
    }
    if (lane == 0) {
      si[grow0 + r] = p1;
      sj[grow0 + r] = p2;
    }
  }
  const int b = grow0 >> 11;
  const int n0 = grow0 & (N_ - 1);
  __align__(16) unsigned short u[8];
#pragma unroll
  for (int r = 0; r < 8; ++r) u[r] = f2bf(acc[r]);
  *(bf16x8*)&WhT[(((size_t)(b * FOUT + f)) << 11) + n0] = *(const bf16x8*)u;
}

// ---------------- Kernel 2: adj -> bitmasks ----------------
__global__ __launch_bounds__(256) void k_pack(
    const int* __restrict__ adj, unsigned long long* __restrict__ mask_rm,
    unsigned int* __restrict__ mask_t) {
  const int lane = threadIdx.x & 63;
  const int wv = threadIdx.x >> 6;
  const int r = blockIdx.x * 4 + wv;
  const int* row = adj + (size_t)r * N_;
  unsigned int wacc = 0;
#pragma unroll
  for (int it = 0; it < 32; ++it) {
    int v = row[it * 64 + lane];
    unsigned long long bm = __ballot(v > 0);
    if (lane == 0) mask_rm[r * 32 + it] = bm;
    wacc |= ((unsigned int)(v > 0)) << it;
  }
  mask_t[r * 64 + lane] = wacc;
}

// ---------------- Kernel 3: per-row softmax stats ----------------
__global__ __launch_bounds__(256) void k_stats(
    const unsigned int* __restrict__ mask_t, const float* __restrict__ si,
    const float* __restrict__ sj, float* __restrict__ mrow,
    float* __restrict__ rrow) {
  const int lane = threadIdx.x & 63;
  const int wv = threadIdx.x >> 6;
  const int row = blockIdx.x * 4 + wv;  // b*N + i
  const int b = row >> 11;
  const int i = row & (N_ - 1);
  const unsigned int w32 = mask_t[i * 64 + lane];
  const float* sjb = sj + ((size_t)b << 11);
  float sjv[32];
  float M = -3.0e38f;
#pragma unroll
  for (int it = 0; it < 32; ++it) {
    sjv[it] = sjb[it * 64 + lane];
    if ((w32 >> it) & 1u) M = fmaxf(M, sjv[it]);
  }
#pragma unroll
  for (int off = 32; off; off >>= 1) M = fmaxf(M, __shfl_xor(M, off));
  const float siv = si[row];
  const float e0 = siv + M;
  const float m = e0 > 0.f ? e0 : ALPHA_ * e0;
  float s = 0.f;
#pragma unroll
  for (int it = 0; it < 32; ++it) {
    float e = siv + sjv[it];
    float v = e > 0.f ? e : ALPHA_ * e;
    float p = __expf(v - m);
    s += ((w32 >> it) & 1u) ? p : 0.f;
  }
#pragma unroll
  for (int off = 32; off; off >>= 1) s += __shfl_xor(s, off);
  if (lane == 0) {
    mrow[row] = m;
    rrow[row] = 1.f / s;
  }
}

// ---------------- Kernel 4a: h' = att @ Wh via MFMA (no att stores) ----------
// Block = 32 rows of one batch, 8 waves; wave wv owns j in [wv*256, +256),
// recomputes att in registers, accumulates partial C; LDS tree-reduce at end.
constexpr int TI = 32;

__global__ __launch_bounds__(512, 4) void k_hp(
    const unsigned short* __restrict__ WhT,
    const unsigned long long* __restrict__ mask_rm,
    const float* __restrict__ si, const float* __restrict__ sjg,
    const float* __restrict__ mrow, const float* __restrict__ rrow,
    float* __restrict__ h_out) {
  __shared__ float red[4][TI][FOUT];  // 32 KB

  const int bid = blockIdx.x;  // 512 blocks
  const int swz = (bid & 7) * 64 + (bid >> 3);  // XCD <-> batch
  const int b = swz >> 6;
  const int i0 = (swz & 63) * TI;

  const int tid = threadIdx.x;
  const int lane = tid & 63;
  const int wv = tid >> 6;
  const int rl = lane & 15;
  const int hi = lane >> 4;
  const int jsl = wv * 256;  // this wave's j-slice

  const int grow0 = (b << 11) + i0 + rl;
  const int grow1 = grow0 + 16;
  const float sir0 = si[grow0], sir1 = si[grow1];
  const float mK0 = mrow[grow0] * 1.44269504f, mK1 = mrow[grow1] * 1.44269504f;
  const float rr0 = rrow[grow0], rr1 = rrow[grow1];
  const float* __restrict__ sjb = sjg + ((size_t)b << 11);

  const unsigned char* maskb = (const unsigned char*)mask_rm;
  const uint4 mA0 = *(const uint4*)(maskb + (i0 + rl) * 256 + (jsl >> 3));
  const uint4 mA1 = *(const uint4*)(maskb + (i0 + rl) * 256 + (jsl >> 3) + 16);
  const uint4 mB0 = *(const uint4*)(maskb + (i0 + 16 + rl) * 256 + (jsl >> 3));
  const uint4 mB1 = *(const uint4*)(maskb + (i0 + 16 + rl) * 256 + (jsl >> 3) + 16);
  const unsigned int mw0[8] = {mA0.x, mA0.y, mA0.z, mA0.w, mA1.x, mA1.y, mA1.z, mA1.w};
  const unsigned int mw1[8] = {mB0.x, mB0.y, mB0.z, mB0.w, mB1.x, mB1.y, mB1.z, mB1.w};

  const unsigned short* wbp[4];
#pragma unroll
  for (int ct = 0; ct < 4; ++ct)
    wbp[ct] = WhT + (((size_t)(b * FOUT + ct * 16 + rl)) << 11) + jsl + hi * 8;

  f32x4 acc[2][4];
#pragma unroll
  for (int rt = 0; rt < 2; ++rt)
#pragma unroll
    for (int ct = 0; ct < 4; ++ct) acc[rt][ct] = (f32x4){0.f, 0.f, 0.f, 0.f};

#pragma unroll
  for (int ks = 0; ks < 8; ++ks) {
    const int jb = jsl + ks * 32 + hi * 8;  // this lane's 8 j's
    const float4 s0 = *(const float4*)(sjb + jb);
    const float4 s1 = *(const float4*)(sjb + jb + 4);
    const float sjl[8] = {s0.x, s0.y, s0.z, s0.w, s1.x, s1.y, s1.z, s1.w};

    bf16x8 afr0, afr1;
    {
      const unsigned int mby = (mw0[ks] >> (hi * 8)) & 0xffu;
      __align__(16) unsigned short u[8];
#pragma unroll
      for (int e = 0; e < 8; ++e) {
        float ev = sir0 + sjl[e];
        float v = fmaxf(ev, ALPHA_ * ev);
        float p = exp2f(fmaf(v, 1.44269504f, -mK0)) * rr0;
        u[e] = ((mby >> e) & 1u) ? f2bf(p) : 0;
      }
      afr0 = *(const bf16x8*)u;
    }
    {
      const unsigned int mby = (mw1[ks] >> (hi * 8)) & 0xffu;
      __align__(16) unsigned short u[8];
#pragma unroll
      for (int e = 0; e < 8; ++e) {
        float ev = sir1 + sjl[e];
        float v = fmaxf(ev, ALPHA_ * ev);
        float p = exp2f(fmaf(v, 1.44269504f, -mK1)) * rr1;
        u[e] = ((mby >> e) & 1u) ? f2bf(p) : 0;
      }
      afr1 = *(const bf16x8*)u;
    }

#pragma unroll
    for (int ct = 0; ct < 4; ++ct) {
      bf16x8 bv = *(const bf16x8*)(wbp[ct] + ks * 32);
      acc[0][ct] = __builtin_amdgcn_mfma_f32_16x16x32_bf16(afr0, bv, acc[0][ct], 0, 0, 0);
      acc[1][ct] = __builtin_amdgcn_mfma_f32_16x16x32_bf16(afr1, bv, acc[1][ct], 0, 0, 0);
    }
  }

  // cross-wave partial-C reduction (tile: row=rt*16+hi*4+reg, col=ct*16+rl)
  if (wv < 4) {
#pragma unroll
    for (int rt = 0; rt < 2; ++rt)
#pragma unroll
      for (int ct = 0; ct < 4; ++ct)
#pragma unroll
        for (int rg = 0; rg < 4; ++rg)
          red[wv][rt * 16 + hi * 4 + rg][ct * 16 + rl] = acc[rt][ct][rg];
  }
  __syncthreads();
  if (wv >= 4) {
#pragma unroll
    for (int rt = 0; rt < 2; ++rt)
#pragma unroll
      for (int ct = 0; ct < 4; ++ct)
#pragma unroll
        for (int rg = 0; rg < 4; ++rg)
          red[wv - 4][rt * 16 + hi * 4 + rg][ct * 16 + rl] += acc[rt][ct][rg];
  }
  __syncthreads();

#pragma unroll
  for (int k = tid; k < TI * FOUT; k += 512) {
    const int r = k >> 6;
    const int c = k & 63;
    float x = red[0][r][c] + red[1][r][c] + red[2][r][c] + red[3][r][c];
    float o = x > 0.f ? x : __expf(x) - 1.f;
    h_out[(((size_t)((b << 11) + i0 + r)) << 6) + c] = o;
  }
}

// ---------------- Kernel 4b: pure attention writer (fill-shaped) ------------
// One wave per att row. Per iter: lane handles 4 consecutive j -> one f32x4
// store; a wave store instruction covers 1 KB fully packed (like the fill).
__global__ __launch_bounds__(256) void k_att(
    const unsigned char* __restrict__ maskb, const float* __restrict__ si,
    const float* __restrict__ sjg, const float* __restrict__ mrow,
    const float* __restrict__ rrow, float* __restrict__ att_out) {
  const int lane = threadIdx.x & 63;
  const int wv = threadIdx.x >> 6;
  const int row = blockIdx.x * 4 + wv;  // b*N + i
  const int b = row >> 11;
  const int i = row & (N_ - 1);
  const float sir = si[row];
  const float mK = mrow[row] * 1.44269504f;
  const float rr = rrow[row];
  const float* __restrict__ sjb = sjg + ((size_t)b << 11);
  const unsigned char* __restrict__ mb = maskb + i * 256;
  float* __restrict__ ao = att_out + ((size_t)row << 11);

#pragma unroll
  for (int it = 0; it < 8; ++it) {
    const int j = it * 256 + lane * 4;
    const float4 s = *(const float4*)(sjb + j);
    const unsigned int mby = mb[it * 32 + (lane >> 1)] >> ((lane & 1) * 4);
    const float sjl[4] = {s.x, s.y, s.z, s.w};
    float av[4];
#pragma unroll
    for (int e = 0; e < 4; ++e) {
      float ev = sir + sjl[e];
      float v = fmaxf(ev, ALPHA_ * ev);
      float p = exp2f(fmaf(v, 1.44269504f, -mK)) * rr;
      av[e] = ((mby >> e) & 1u) ? p : 0.f;
    }
    f32x4 vv = {av[0], av[1], av[2], av[3]};
    *(f32x4*)(ao + j) = vv;
  }
}

extern "C" void kernel_launch(void* const* d_in, const int* in_sizes, int n_in,
                              void* d_out, int out_size, void* d_ws, size_t ws_size,
                              hipStream_t stream) {
  const float* h = (const float*)d_in[0];
  const int* adj = (const int*)d_in[1];
  const float* W = (const float*)d_in[2];
  const float* a = (const float*)d_in[3];

  float* out = (float*)d_out;
  float* h_out = out;                             // B*N*FOUT
  float* att_out = out + (size_t)B_ * N_ * FOUT;  // B*N*N

  unsigned short* WhT = (unsigned short*)d_ws;                       // 2 MB
  float* si = (float*)((char*)d_ws + (size_t)2 * 1024 * 1024);       // 64 KB
  float* sj = si + B_ * N_;                                          // 64 KB
  float* mrow = sj + B_ * N_;                                        // 64 KB
  float* rrow = mrow + B_ * N_;                                      // 64 KB
  unsigned long long* mask_rm = (unsigned long long*)(rrow + B_ * N_);  // 512 KB
  unsigned int* mask_t = (unsigned int*)((char*)mask_rm + (size_t)N_ * 32 * 8);  // 512 KB

  k_wh<<<B_ * N_ / 32, 256, 0, stream>>>(h, W, a, WhT, si, sj);
  k_pack<<<N_ / 4, 256, 0, stream>>>(adj, mask_rm, mask_t);
  k_stats<<<B_ * N_ / 4, 256, 0, stream>>>(mask_t, si, sj, mrow, rrow);
  k_hp<<<B_ * (N_ / TI), 512, 0, stream>>>(WhT, mask_rm, si, sj, mrow, rrow,
                                           h_out);
  k_att<<<B_ * N_ / 4, 256, 0, stream>>>((const unsigned char*)mask_rm, si, sj,
                                         mrow, rrow, att_out);
}